// Round 2
// baseline (350.676 us; speedup 1.0000x reference)
//
#include <hip/hip_runtime.h>

#define NK 512
#define ND 64
#define NHW 4096
#define NPIX 131072            // 32*64*64
#define OUT_ELEMS 8388608      // 32*64*64*64

// ---------------------------------------------------------------------------
// Prep: sc[k] = numpy-pairwise-8 fp32 sum of fl(c_d^2)  (emulates
// np.sum(cb*cb, axis=1)); also zero the two loss slots in d_out (harness
// re-poisons d_out/d_ws to 0xAA before every timed replay).
// ---------------------------------------------------------------------------
__global__ __launch_bounds__(256) void vq_prep(const float* __restrict__ cb,
                                               float* __restrict__ sc,
                                               float* __restrict__ losses) {
#pragma clang fp contract(off)
  {
    int k = blockIdx.x * 256 + threadIdx.x;   // grid 2*256 = 512
    const float* c = cb + (size_t)k * ND;
    float q[ND];
#pragma unroll
    for (int d = 0; d < ND; ++d) q[d] = c[d] * c[d];  // rounded squares first
    float r[8];
#pragma unroll
    for (int j = 0; j < 8; ++j) r[j] = q[j];
#pragma unroll
    for (int i = 8; i < ND; i += 8)
#pragma unroll
      for (int j = 0; j < 8; ++j) r[j] += q[i + j];
    float res = ((r[0] + r[1]) + (r[2] + r[3])) + ((r[4] + r[5]) + (r[6] + r[7]));
    sc[k] = res;
    if (k < 2) losses[k] = 0.f;
  }
}

// ---------------------------------------------------------------------------
// Main: one thread per pixel. Emulates the np fp32 reference bitwise:
//   d2[k] = fl( fl( Sx - fl(2*M[k]) ) + Sc[k] ),  M[k] = sequential-FMA dot
// (BLAS micro-kernel order), Sx = numpy pairwise-8 sum of fl(x_d^2).
// argmin with strict '<' (lowest index wins ties, = np.argmin).
// NO exact/fp64 refinement: the reference's own fp32 rounding noise around
// |x|^2 ~ 64 (ulp 7.6e-6) IS the decision function we must reproduce.
// ---------------------------------------------------------------------------
__global__ __launch_bounds__(256) void vq_main(const float* __restrict__ x,
                                               const float* __restrict__ cb,
                                               const float* __restrict__ sc,
                                               float* __restrict__ out,
                                               float* __restrict__ idx_out,
                                               float* __restrict__ losses) {
#pragma clang fp contract(off)
  {
    const int g = blockIdx.x * 256 + threadIdx.x;
    const int b = g >> 12;
    const int hw = g & 4095;
    const float* xp = x + (size_t)b * (ND * NHW) + hw;

    float xr[ND];
#pragma unroll
    for (int d = 0; d < ND; ++d) xr[d] = xp[(size_t)d * NHW];  // coalesced

    // Sx = np.sum(x*x) : rounded squares, then pairwise-8 adds.
    float r[8];
#pragma unroll
    for (int j = 0; j < 8; ++j) r[j] = xr[j] * xr[j];
#pragma unroll
    for (int i = 8; i < ND; i += 8)
#pragma unroll
      for (int j = 0; j < 8; ++j) r[j] += xr[i + j] * xr[i + j];
    const float Sx = ((r[0] + r[1]) + (r[2] + r[3])) + ((r[4] + r[5]) + (r[6] + r[7]));

    float m1 = 3.0e38f;
    int i1 = 0;

    for (int k = 0; k < NK; k += 4) {           // 4 sequential chains for ILP
      const float* c0 = cb + (size_t)(k + 0) * ND;   // wave-uniform -> s_load
      const float* c1 = cb + (size_t)(k + 1) * ND;
      const float* c2 = cb + (size_t)(k + 2) * ND;
      const float* c3 = cb + (size_t)(k + 3) * ND;
      float a0 = 0.f, a1 = 0.f, a2 = 0.f, a3 = 0.f;
#pragma unroll
      for (int d = 0; d < ND; ++d) {            // sequential FMA chain = BLAS
        a0 = __builtin_fmaf(c0[d], xr[d], a0);
        a1 = __builtin_fmaf(c1[d], xr[d], a1);
        a2 = __builtin_fmaf(c2[d], xr[d], a2);
        a3 = __builtin_fmaf(c3[d], xr[d], a3);
      }
      // d2 = (Sx - 2*M) + Sc, each op rounded fp32 (2*M exact).
      float d20 = (Sx - 2.0f * a0) + sc[k + 0];
      float d21 = (Sx - 2.0f * a1) + sc[k + 1];
      float d22 = (Sx - 2.0f * a2) + sc[k + 2];
      float d23 = (Sx - 2.0f * a3) + sc[k + 3];
      if (d20 < m1) { m1 = d20; i1 = k + 0; }   // in-order: lowest index wins
      if (d21 < m1) { m1 = d21; i1 = k + 1; }
      if (d22 < m1) { m1 = d22; i1 = k + 2; }
      if (d23 < m1) { m1 = d23; i1 = k + 3; }
    }

    // Gather chosen code (128 KB codebook, L2-resident), write transposed
    // output, accumulate loss partial sum_d (x_d - q_d)^2.
    const float4* q4 = (const float4*)(cb + (size_t)i1 * ND);
    float* op = out + (size_t)b * (ND * NHW) + hw;
    float lossp = 0.f;
#pragma unroll
    for (int d4 = 0; d4 < ND / 4; ++d4) {
      float4 q = q4[d4];
      int d = d4 * 4;
      float e;
      e = xr[d + 0] - q.x; lossp = __builtin_fmaf(e, e, lossp); op[(size_t)(d + 0) * NHW] = q.x;
      e = xr[d + 1] - q.y; lossp = __builtin_fmaf(e, e, lossp); op[(size_t)(d + 1) * NHW] = q.y;
      e = xr[d + 2] - q.z; lossp = __builtin_fmaf(e, e, lossp); op[(size_t)(d + 2) * NHW] = q.z;
      e = xr[d + 3] - q.w; lossp = __builtin_fmaf(e, e, lossp); op[(size_t)(d + 3) * NHW] = q.w;
    }
    idx_out[g] = (float)i1;   // concat buffer is read back as fp32

    // Block loss reduction, one atomic pair per block (512 blocks).
#pragma unroll
    for (int off = 32; off; off >>= 1) lossp += __shfl_down(lossp, off);
    __shared__ float red[4];
    const int lane = threadIdx.x & 63, wid = threadIdx.x >> 6;
    if (lane == 0) red[wid] = lossp;
    __syncthreads();
    if (threadIdx.x == 0) {
      float t = (red[0] + red[1] + red[2] + red[3]) * (1.f / 8388608.f);
      atomicAdd(losses + 0, t);   // dictionary_loss
      atomicAdd(losses + 1, t);   // commitment_loss (identical forward value)
    }
  }
}

extern "C" void kernel_launch(void* const* d_in, const int* in_sizes, int n_in,
                              void* d_out, int out_size, void* d_ws, size_t ws_size,
                              hipStream_t stream) {
  const float* x  = (const float*)d_in[0];   // [32,64,64,64] fp32
  const float* cb = (const float*)d_in[1];   // [512,64] fp32
  float* out     = (float*)d_out;            // quantized [B,D,H,W]
  float* idx_out = out + OUT_ELEMS;          // indices (as fp32) [B,H,W]
  float* losses  = idx_out + NPIX;           // 2 scalars
  float* sc      = (float*)d_ws;             // 512 floats scratch

  vq_prep<<<2, 256, 0, stream>>>(cb, sc, losses);
  vq_main<<<NPIX / 256, 256, 0, stream>>>(x, cb, sc, out, idx_out, losses);
}